// Round 7
// baseline (273.516 us; speedup 1.0000x reference)
//
#include <hip/hip_runtime.h>
#include <math.h>

#define B_      4
#define IN_DIM  512
#define HID     1024
#define SEQ     4096
#define RH      64
#define RL      2
#define MID_DIM 12352          // 2*64*64 + 65*64
#define OUT_DIM 193            // 2*64 + 65
#define MLP_OUT 24897          // RL*MID_DIM + OUT_DIM
#define INV2PI  0.15915494309189535f
#define MLPT_STRIDE 25088
#define KSPLIT3 32             // k-split for gemm3: 32 chunks of 32

// ---- workspace layout (float offsets) ----
#define OFF_P0    0            // 8*4*1024    = 32768
#define OFF_P1    32768        // 16*4*1024   = 65536
#define OFF_P2    98304        // 16*4*1024   = 65536
#define OFF_H2    163840       // 4096
#define OFF_P3    167936       // 32*4*24897  = 3186816
#define OFF_MLPT  3354752      // 4*25088     = 100352

// 16B vector with only 4B alignment guarantee (w3 rows have odd stride 24897)
typedef float float4a __attribute__((ext_vector_type(4), aligned(4)));

__device__ __forceinline__ float gelu_exact(float v) {
    return 0.5f * v * (1.0f + erff(v * 0.70710678118654752f));
}

__device__ __forceinline__ float hw_sin_rev(float r) {
    r = r - __builtin_rintf(r);
    return __builtin_amdgcn_sinf(r);
}

// ============================================================================
// k_gemm0: x(4x512) @ w0, split-K 8.  grid (16, 8), block 256.  [verified]
// ============================================================================
__global__ void __launch_bounds__(256) k_gemm0(
        const float* __restrict__ x, const float* __restrict__ w0,
        float* __restrict__ p0) {
    const int cch = blockIdx.x, kc = blockIdx.y, tid = threadIdx.x;
    __shared__ float xs[256];                 // [b][k]
    {
        const int b = tid >> 6, k = tid & 63;
        xs[tid] = x[b * IN_DIM + kc * 64 + k];
    }
    __syncthreads();
    const int b = tid >> 6, cl = tid & 63;
    const int c = cch * 64 + cl;
    const float* wp = w0 + (size_t)(kc * 64) * HID + c;
    const float* xp = xs + b * 64;
    float acc = 0.f;
    #pragma unroll 8
    for (int k = 0; k < 64; ++k)
        acc = fmaf(xp[k], wp[(size_t)k * HID], acc);
    p0[(kc * 4 + b) * HID + c] = acc;
}

// ============================================================================
// k_gemm1: h0=gelu(sum8 p0 + b0); h0 @ w1.  grid (16, 16), block 256. [verified]
// ============================================================================
__global__ void __launch_bounds__(256) k_gemm1(
        const float* __restrict__ p0, const float* __restrict__ b0,
        const float* __restrict__ w1, float* __restrict__ p1) {
    const int cch = blockIdx.x, kc = blockIdx.y, tid = threadIdx.x;
    __shared__ float hs[256];                 // [b][k]
    {
        const int b = tid >> 6, k = tid & 63;
        const int kg = kc * 64 + k;
        float v = b0[kg];
        #pragma unroll
        for (int j = 0; j < 8; ++j) v += p0[(j * 4 + b) * HID + kg];
        hs[tid] = gelu_exact(v);
    }
    __syncthreads();
    const int b = tid >> 6, cl = tid & 63;
    const int c = cch * 64 + cl;
    const float* wp = w1 + (size_t)(kc * 64) * HID + c;
    const float* hp = hs + b * 64;
    float acc = 0.f;
    #pragma unroll 8
    for (int k = 0; k < 64; ++k)
        acc = fmaf(hp[k], wp[(size_t)k * HID], acc);
    p1[(kc * 4 + b) * HID + c] = acc;
}

// ============================================================================
// k_B: fused LN1+gelu+gemm2.  grid (cch=16, kc=16), block 256.  [verified]
// ============================================================================
__global__ void __launch_bounds__(256) k_B(
        const float* __restrict__ p1, const float* __restrict__ b1,
        const float* __restrict__ g1, const float* __restrict__ bl1,
        const float* __restrict__ w2, float* __restrict__ p2) {
    const int cch = blockIdx.x, kc = blockIdx.y, tid = threadIdx.x;
    __shared__ float h1s[256];
    const int b = tid >> 6, lane = tid & 63;

    float s1 = 0.f, s2 = 0.f;
    #pragma unroll
    for (int q = 0; q < 16; ++q) {
        const int c = q * 64 + lane;
        float v = b1[c];
        #pragma unroll
        for (int j = 0; j < 16; ++j) v += p1[(j * 4 + b) * HID + c];
        s1 += v; s2 += v * v;
    }
    #pragma unroll
    for (int m = 1; m < 64; m <<= 1) {
        s1 += __shfl_xor(s1, m, 64);
        s2 += __shfl_xor(s2, m, 64);
    }
    const float mu = s1 * (1.0f / HID);
    const float rs = rsqrtf(s2 * (1.0f / HID) - mu * mu + 1e-5f);

    {
        const int k = kc * 64 + lane;
        float v = b1[k];
        #pragma unroll
        for (int j = 0; j < 16; ++j) v += p1[(j * 4 + b) * HID + k];
        h1s[tid] = gelu_exact((v - mu) * rs * g1[k] + bl1[k]);
    }
    __syncthreads();

    {
        const int c = cch * 64 + lane;
        const float* wp = w2 + (size_t)(kc * 64) * HID + c;
        const float* hp = h1s + b * 64;
        float acc = 0.f;
        #pragma unroll 8
        for (int k = 0; k < 64; ++k)
            acc = fmaf(hp[k], wp[(size_t)k * HID], acc);
        p2[(kc * 4 + b) * HID + c] = acc;
    }
}

// ============================================================================
// k_lng: combine 16 partials + bias -> LN -> gelu -> h2.  grid 4, block 1024.
// [verified]
// ============================================================================
__global__ void k_lng(const float* __restrict__ part, const float* __restrict__ bias,
                      const float* __restrict__ g, const float* __restrict__ bl,
                      float* __restrict__ h) {
    const int b = blockIdx.x, tid = threadIdx.x;
    float v = bias[tid];
    #pragma unroll
    for (int j = 0; j < 16; ++j) v += part[(j * 4 + b) * HID + tid];
    float s1 = v, s2 = v * v;
    #pragma unroll
    for (int m = 1; m < 64; m <<= 1) {
        s1 += __shfl_xor(s1, m, 64);
        s2 += __shfl_xor(s2, m, 64);
    }
    __shared__ float r1[16], r2[16], s_mu, s_rs;
    const int lane = tid & 63, wid = tid >> 6;
    if (lane == 0) { r1[wid] = s1; r2[wid] = s2; }
    __syncthreads();
    if (tid == 0) {
        float a = 0.f, c = 0.f;
        #pragma unroll
        for (int j = 0; j < 16; ++j) { a += r1[j]; c += r2[j]; }
        const float mu = a * (1.0f / HID);
        s_mu = mu;
        s_rs = rsqrtf(c * (1.0f / HID) - mu * mu + 1e-5f);
    }
    __syncthreads();
    h[b * HID + tid] = gelu_exact((v - s_mu) * s_rs * g[tid] + bl[tid]);
}

// ============================================================================
// k_gemm3v: h2(4x1024) @ w3, split-K 32, float4-per-thread columns.
// grid (25, 32) = 800 blocks, block 256.  Each thread owns 4 consecutive
// c (16B/lane loads, 4KB/wave contiguous per k-step — G13 sweet spot).
// w3 rows only 4B-aligned (MLP_OUT odd) -> float4a loads.
// ============================================================================
__global__ void __launch_bounds__(256) k_gemm3v(
        const float* __restrict__ h2, const float* __restrict__ w3,
        float* __restrict__ p3) {
    const int cch = blockIdx.x, kc = blockIdx.y, tid = threadIdx.x;
    __shared__ float hs[128];                  // [b][32] this k-chunk
    if (tid < 128) {
        const int b = tid >> 5, k = tid & 31;
        hs[tid] = h2[b * HID + kc * 32 + k];
    }
    __syncthreads();
    const int c0 = cch * 1024 + tid * 4;
    if (c0 >= MLP_OUT) return;
    const float* wp = w3 + (size_t)(kc * 32) * MLP_OUT;
    if (c0 + 3 < MLP_OUT) {
        float4a a0 = {0.f, 0.f, 0.f, 0.f}, a1 = a0, a2 = a0, a3 = a0;
        #pragma unroll 8
        for (int k = 0; k < 32; ++k) {
            const float4a w = *reinterpret_cast<const float4a*>(
                                  &wp[(size_t)k * MLP_OUT + c0]);
            const float h0 = hs[k], h1 = hs[32 + k],
                        h2v = hs[64 + k], h3 = hs[96 + k];
            #pragma unroll
            for (int e = 0; e < 4; ++e) {
                a0[e] = fmaf(h0,  w[e], a0[e]);
                a1[e] = fmaf(h1,  w[e], a1[e]);
                a2[e] = fmaf(h2v, w[e], a2[e]);
                a3[e] = fmaf(h3,  w[e], a3[e]);
            }
        }
        *reinterpret_cast<float4a*>(&p3[(size_t)(kc * 4 + 0) * MLP_OUT + c0]) = a0;
        *reinterpret_cast<float4a*>(&p3[(size_t)(kc * 4 + 1) * MLP_OUT + c0]) = a1;
        *reinterpret_cast<float4a*>(&p3[(size_t)(kc * 4 + 2) * MLP_OUT + c0]) = a2;
        *reinterpret_cast<float4a*>(&p3[(size_t)(kc * 4 + 3) * MLP_OUT + c0]) = a3;
    } else {
        // scalar tail: the single last column (MLP_OUT % 4 == 1)
        float s0 = 0.f, s1 = 0.f, s2 = 0.f, s3 = 0.f;
        #pragma unroll 8
        for (int k = 0; k < 32; ++k) {
            const float w = wp[(size_t)k * MLP_OUT + c0];
            s0 = fmaf(hs[k],      w, s0);
            s1 = fmaf(hs[32 + k], w, s1);
            s2 = fmaf(hs[64 + k], w, s2);
            s3 = fmaf(hs[96 + k], w, s3);
        }
        p3[(size_t)(kc * 4 + 0) * MLP_OUT + c0] = s0;
        p3[(size_t)(kc * 4 + 1) * MLP_OUT + c0] = s1;
        p3[(size_t)(kc * 4 + 2) * MLP_OUT + c0] = s2;
        p3[(size_t)(kc * 4 + 3) * MLP_OUT + c0] = s3;
    }
}

// ============================================================================
// k_comb3T: combine 32 partials + bias -> transposed, pre-scaled layout.
// grid (98, 4), block 256.  [verified map; partial count 16 -> 32]
// ============================================================================
__global__ void k_comb3T(const float* __restrict__ p3, const float* __restrict__ b3,
                         float* __restrict__ mlpT) {
    const int d = blockIdx.x * 256 + threadIdx.x;   // < 25088
    const int b = blockIdx.y;
    int src = -1;
    float scale = 1.f;
    if (d < 24832) {
        const int l = d / 12416, r = d % 12416;
        const int base = l * MID_DIM;
        if (r < 8192) {                       // wsc / wof
            const int half = r >> 12;
            const int rr = r & 4095;
            const int i = rr >> 6, o = rr & 63;
            src = base + o * 128 + i * 2 + half;
            scale = INV2PI;
        } else if (r < 12288) {               // bsv
            const int rr = r - 8192;
            const int i = rr >> 6, o = rr & 63;
            src = base + 8192 + o * 65 + 1 + i;
        } else if (r < 12352) {               // bc
            const int o = r - 12288;
            src = base + 8192 + o * 65;
        }
    } else {
        const int rr = d - 24832;
        const int base = RL * MID_DIM;        // 24704
        if (rr < 64)        { src = base + rr * 2;            scale = INV2PI; }
        else if (rr < 128)  { src = base + (rr - 64) * 2 + 1; scale = INV2PI; }
        else if (rr < 192)  { src = base + 128 + 1 + (rr - 128); }
        else if (rr == 192) { src = base + 128; }
    }
    float v = 0.f;
    if (src >= 0) {
        v = b3[src];
        #pragma unroll
        for (int j = 0; j < KSPLIT3; ++j)
            v += p3[(size_t)(j * 4 + b) * MLP_OUT + src];
        v *= scale;
    }
    mlpT[(size_t)b * MLPT_STRIDE + d] = v;
}

// ============================================================================
// k_ripple: fully fused ripple.  grid (SEQ/32, B), block 256.  [verified]
// ============================================================================
__global__ void __launch_bounds__(256, 2) k_ripple(
        const float* __restrict__ mlpT, const float* __restrict__ lcw,
        const float* __restrict__ lcb, const float* __restrict__ bypw,
        const float* __restrict__ bypb, float* __restrict__ out) {
    const int tid = threadIdx.x;
    const int b = blockIdx.y;
    const int t0 = blockIdx.x * 32;
    const int lane = tid & 63, wid = tid >> 6, tb = wid * 8;

    __shared__ __align__(16) float s_w[12416];
    __shared__ __align__(16) float s_x[64 * 36];
    __shared__ __align__(16) float s_wo[256];
    __shared__ float s_red[32];

    const float* mb = mlpT + (size_t)b * MLPT_STRIDE;

    {
        const float4* src = reinterpret_cast<const float4*>(mb);
        float4* dst = reinterpret_cast<float4*>(s_w);
        for (int e = tid; e < 3104; e += 256) dst[e] = src[e];
        if (tid < 64) {
            reinterpret_cast<float4*>(s_wo)[tid] =
                reinterpret_cast<const float4*>(mb + 24832)[tid];
        }
    }
    const float lw = lcw[lane], lb = lcb[lane];
    for (int e = tid; e < 2048; e += 256) {
        const int i = e >> 5, tt = e & 31;
        s_x[i * 36 + tt] = fmaf((float)(t0 + tt), lcw[i], lcb[i]);
    }
    __syncthreads();

    float acc[8];
    for (int layer = 0; layer < 2; ++layer) {
        const float bc = s_w[12288 + lane];
        #pragma unroll
        for (int j = 0; j < 8; ++j) acc[j] = bc;
        for (int i = 0; i < 64; ++i) {
            const float ws_ = s_w[i * 64 + lane];
            const float wo_ = s_w[4096 + i * 64 + lane];
            const float bs_ = s_w[8192 + i * 64 + lane];
            const float4 xa = *reinterpret_cast<const float4*>(&s_x[i * 36 + tb]);
            const float4 xb = *reinterpret_cast<const float4*>(&s_x[i * 36 + tb + 4]);
            const float xv[8] = {xa.x, xa.y, xa.z, xa.w, xb.x, xb.y, xb.z, xb.w};
            #pragma unroll
            for (int j = 0; j < 8; ++j) {
                const float r = fmaf(ws_, xv[j], wo_);
                acc[j] = fmaf(hw_sin_rev(r), bs_, acc[j]);
            }
        }
        __syncthreads();
        if (layer == 0) {
            #pragma unroll
            for (int j = 0; j < 8; ++j)
                s_x[lane * 36 + tb + j] = gelu_exact(acc[j]);
            const float4* src = reinterpret_cast<const float4*>(mb + 12416);
            float4* dst = reinterpret_cast<float4*>(s_w);
            for (int e = tid; e < 3104; e += 256) dst[e] = src[e];
            __syncthreads();
        }
    }

    {
        const float wsO = s_wo[lane], woO = s_wo[64 + lane], bsO = s_wo[128 + lane];
        const float bcO = s_wo[192];
        const float bw0 = bypw[0] * INV2PI, bw1 = bypw[1] * INV2PI;
        const float bb0 = bypb[0], bb1 = bypb[1];
        #pragma unroll
        for (int j = 0; j < 8; ++j) {
            const int t = t0 + tb + j;
            const float v = gelu_exact(acc[j]);
            float s = hw_sin_rev(fmaf(wsO, v, woO)) * bsO;
            const float xbv = fmaf((float)t, lw, lb);
            s = fmaf(hw_sin_rev(fmaf(bw0, xbv, bw1)), bb1, s);
            #pragma unroll
            for (int m = 1; m < 64; m <<= 1) s += __shfl_xor(s, m, 64);
            if (lane == 0) s_red[tb + j] = s + bcO + bb0;
        }
    }
    __syncthreads();
    if (tid < 32) out[(size_t)b * SEQ + t0 + tid] = s_red[tid];
}

extern "C" void kernel_launch(void* const* d_in, const int* in_sizes, int n_in,
                              void* d_out, int out_size, void* d_ws, size_t ws_size,
                              hipStream_t stream) {
    const float* x     = (const float*)d_in[0];
    const float* w0    = (const float*)d_in[1];
    const float* b0    = (const float*)d_in[2];
    const float* w1    = (const float*)d_in[3];
    const float* b1    = (const float*)d_in[4];
    const float* g1    = (const float*)d_in[5];
    const float* bln1  = (const float*)d_in[6];
    const float* w2    = (const float*)d_in[7];
    const float* b2    = (const float*)d_in[8];
    const float* g2    = (const float*)d_in[9];
    const float* bln2  = (const float*)d_in[10];
    const float* w3    = (const float*)d_in[11];
    const float* b3    = (const float*)d_in[12];
    const float* lcw   = (const float*)d_in[13];
    const float* lcb   = (const float*)d_in[14];
    const float* bypw  = (const float*)d_in[15];
    const float* bypb  = (const float*)d_in[16];
    float* out = (float*)d_out;
    float* ws  = (float*)d_ws;

    float* p0   = ws + OFF_P0;
    float* p1   = ws + OFF_P1;
    float* p2   = ws + OFF_P2;
    float* h2   = ws + OFF_H2;
    float* p3   = ws + OFF_P3;
    float* mlpT = ws + OFF_MLPT;

    k_gemm0  <<<dim3(16, 8),        256, 0, stream>>>(x, w0, p0);
    k_gemm1  <<<dim3(16, 16),       256, 0, stream>>>(p0, b0, w1, p1);
    k_B      <<<dim3(16, 16),       256, 0, stream>>>(p1, b1, g1, bln1, w2, p2);
    k_lng    <<<B_, 1024,           0, stream>>>(p2, b2, g2, bln2, h2);
    k_gemm3v <<<dim3(25, KSPLIT3),  256, 0, stream>>>(h2, w3, p3);
    k_comb3T <<<dim3(98, B_),       256, 0, stream>>>(p3, b3, mlpT);
    k_ripple <<<dim3(SEQ / 32, B_), 256, 0, stream>>>(mlpT, lcw, lcb, bypw, bypb, out);
}

// Round 8
// 257.288 us; speedup vs baseline: 1.0631x; 1.0631x over previous
//
#include <hip/hip_runtime.h>
#include <math.h>

#define B_      4
#define IN_DIM  512
#define HID     1024
#define SEQ     4096
#define RH      64
#define RL      2
#define MID_DIM 12352          // 2*64*64 + 65*64
#define OUT_DIM 193            // 2*64 + 65
#define MLP_OUT 24897          // RL*MID_DIM + OUT_DIM
#define INV2PI  0.15915494309189535f
#define MLPT_STRIDE 25088
#define KSPLIT3 16             // k-split for gemm3: 16 chunks of 64

// ---- workspace layout (float offsets) ----
#define OFF_P0    0            // 8*4*1024   = 32768
#define OFF_P1    32768        // 16*4*1024  = 65536
#define OFF_P2    98304        // 16*4*1024  = 65536
#define OFF_H2    163840       // 4096
#define OFF_P3    167936       // 16*4*24897 = 1593408
#define OFF_MLPT  1761344      // 4*25088    = 100352

__device__ __forceinline__ float gelu_exact(float v) {
    return 0.5f * v * (1.0f + erff(v * 0.70710678118654752f));
}

__device__ __forceinline__ float hw_sin_rev(float r) {
    r = r - __builtin_rintf(r);
    return __builtin_amdgcn_sinf(r);
}

// ============================================================================
// k_gemm0: x(4x512) @ w0, split-K 8.  grid (16, 8), block 256.  [verified]
// ============================================================================
__global__ void __launch_bounds__(256) k_gemm0(
        const float* __restrict__ x, const float* __restrict__ w0,
        float* __restrict__ p0) {
    const int cch = blockIdx.x, kc = blockIdx.y, tid = threadIdx.x;
    __shared__ float xs[256];                 // [b][k]
    {
        const int b = tid >> 6, k = tid & 63;
        xs[tid] = x[b * IN_DIM + kc * 64 + k];
    }
    __syncthreads();
    const int b = tid >> 6, cl = tid & 63;
    const int c = cch * 64 + cl;
    const float* wp = w0 + (size_t)(kc * 64) * HID + c;
    const float* xp = xs + b * 64;
    float acc = 0.f;
    #pragma unroll 8
    for (int k = 0; k < 64; ++k)
        acc = fmaf(xp[k], wp[(size_t)k * HID], acc);
    p0[(kc * 4 + b) * HID + c] = acc;
}

// ============================================================================
// k_gemm1: h0=gelu(sum8 p0 + b0); h0 @ w1.  grid (16, 16), block 256. [verified]
// ============================================================================
__global__ void __launch_bounds__(256) k_gemm1(
        const float* __restrict__ p0, const float* __restrict__ b0,
        const float* __restrict__ w1, float* __restrict__ p1) {
    const int cch = blockIdx.x, kc = blockIdx.y, tid = threadIdx.x;
    __shared__ float hs[256];                 // [b][k]
    {
        const int b = tid >> 6, k = tid & 63;
        const int kg = kc * 64 + k;
        float v = b0[kg];
        #pragma unroll
        for (int j = 0; j < 8; ++j) v += p0[(j * 4 + b) * HID + kg];
        hs[tid] = gelu_exact(v);
    }
    __syncthreads();
    const int b = tid >> 6, cl = tid & 63;
    const int c = cch * 64 + cl;
    const float* wp = w1 + (size_t)(kc * 64) * HID + c;
    const float* hp = hs + b * 64;
    float acc = 0.f;
    #pragma unroll 8
    for (int k = 0; k < 64; ++k)
        acc = fmaf(hp[k], wp[(size_t)k * HID], acc);
    p1[(kc * 4 + b) * HID + c] = acc;
}

// ============================================================================
// k_B: fused LN1+gelu+gemm2.  grid (cch=16, kc=16), block 256.  [verified]
// ============================================================================
__global__ void __launch_bounds__(256) k_B(
        const float* __restrict__ p1, const float* __restrict__ b1,
        const float* __restrict__ g1, const float* __restrict__ bl1,
        const float* __restrict__ w2, float* __restrict__ p2) {
    const int cch = blockIdx.x, kc = blockIdx.y, tid = threadIdx.x;
    __shared__ float h1s[256];
    const int b = tid >> 6, lane = tid & 63;

    float s1 = 0.f, s2 = 0.f;
    #pragma unroll
    for (int q = 0; q < 16; ++q) {
        const int c = q * 64 + lane;
        float v = b1[c];
        #pragma unroll
        for (int j = 0; j < 16; ++j) v += p1[(j * 4 + b) * HID + c];
        s1 += v; s2 += v * v;
    }
    #pragma unroll
    for (int m = 1; m < 64; m <<= 1) {
        s1 += __shfl_xor(s1, m, 64);
        s2 += __shfl_xor(s2, m, 64);
    }
    const float mu = s1 * (1.0f / HID);
    const float rs = rsqrtf(s2 * (1.0f / HID) - mu * mu + 1e-5f);

    {
        const int k = kc * 64 + lane;
        float v = b1[k];
        #pragma unroll
        for (int j = 0; j < 16; ++j) v += p1[(j * 4 + b) * HID + k];
        h1s[tid] = gelu_exact((v - mu) * rs * g1[k] + bl1[k]);
    }
    __syncthreads();

    {
        const int c = cch * 64 + lane;
        const float* wp = w2 + (size_t)(kc * 64) * HID + c;
        const float* hp = h1s + b * 64;
        float acc = 0.f;
        #pragma unroll 8
        for (int k = 0; k < 64; ++k)
            acc = fmaf(hp[k], wp[(size_t)k * HID], acc);
        p2[(kc * 4 + b) * HID + c] = acc;
    }
}

// ============================================================================
// k_lng: combine 16 partials + bias -> LN -> gelu -> h2.  grid 4, block 1024.
// [verified]
// ============================================================================
__global__ void k_lng(const float* __restrict__ part, const float* __restrict__ bias,
                      const float* __restrict__ g, const float* __restrict__ bl,
                      float* __restrict__ h) {
    const int b = blockIdx.x, tid = threadIdx.x;
    float v = bias[tid];
    #pragma unroll
    for (int j = 0; j < 16; ++j) v += part[(j * 4 + b) * HID + tid];
    float s1 = v, s2 = v * v;
    #pragma unroll
    for (int m = 1; m < 64; m <<= 1) {
        s1 += __shfl_xor(s1, m, 64);
        s2 += __shfl_xor(s2, m, 64);
    }
    __shared__ float r1[16], r2[16], s_mu, s_rs;
    const int lane = tid & 63, wid = tid >> 6;
    if (lane == 0) { r1[wid] = s1; r2[wid] = s2; }
    __syncthreads();
    if (tid == 0) {
        float a = 0.f, c = 0.f;
        #pragma unroll
        for (int j = 0; j < 16; ++j) { a += r1[j]; c += r2[j]; }
        const float mu = a * (1.0f / HID);
        s_mu = mu;
        s_rs = rsqrtf(c * (1.0f / HID) - mu * mu + 1e-5f);
    }
    __syncthreads();
    h[b * HID + tid] = gelu_exact((v - s_mu) * s_rs * g[tid] + bl[tid]);
}

// ============================================================================
// k_gemm3s: h2(4x1024) @ w3, split-K 16.  grid (98, 16), block 256.
// 4B/lane dense coalescing — optimal for odd-stride (24897) w3 rows:
// 16B vectors can't fuse (alignment parity flips per row; R7 evidence).
// [verified R6]
// ============================================================================
__global__ void __launch_bounds__(256) k_gemm3s(
        const float* __restrict__ h2, const float* __restrict__ w3,
        float* __restrict__ p3) {
    const int cch = blockIdx.x, kc = blockIdx.y, tid = threadIdx.x;
    __shared__ float hs[256];                  // [b][64] for this k-chunk
    {
        const int b = tid >> 6, k = tid & 63;
        hs[tid] = h2[b * HID + kc * 64 + k];
    }
    __syncthreads();
    const int c = cch * 256 + tid;
    if (c >= MLP_OUT) return;
    const float* wp = w3 + (size_t)(kc * 64) * MLP_OUT + c;
    float a0 = 0.f, a1 = 0.f, a2 = 0.f, a3 = 0.f;
    #pragma unroll 16
    for (int k = 0; k < 64; ++k) {
        const float w = wp[(size_t)k * MLP_OUT];
        a0 = fmaf(hs[k],       w, a0);
        a1 = fmaf(hs[64 + k],  w, a1);
        a2 = fmaf(hs[128 + k], w, a2);
        a3 = fmaf(hs[192 + k], w, a3);
    }
    p3[(size_t)(kc * 4 + 0) * MLP_OUT + c] = a0;
    p3[(size_t)(kc * 4 + 1) * MLP_OUT + c] = a1;
    p3[(size_t)(kc * 4 + 2) * MLP_OUT + c] = a2;
    p3[(size_t)(kc * 4 + 3) * MLP_OUT + c] = a3;
}

// ============================================================================
// k_comb3T: combine 16 partials + bias -> transposed, pre-scaled layout.
// grid (98, 4), block 256.  [verified]
// ============================================================================
__global__ void k_comb3T(const float* __restrict__ p3, const float* __restrict__ b3,
                         float* __restrict__ mlpT) {
    const int d = blockIdx.x * 256 + threadIdx.x;   // < 25088
    const int b = blockIdx.y;
    int src = -1;
    float scale = 1.f;
    if (d < 24832) {
        const int l = d / 12416, r = d % 12416;
        const int base = l * MID_DIM;
        if (r < 8192) {                       // wsc / wof
            const int half = r >> 12;
            const int rr = r & 4095;
            const int i = rr >> 6, o = rr & 63;
            src = base + o * 128 + i * 2 + half;
            scale = INV2PI;
        } else if (r < 12288) {               // bsv
            const int rr = r - 8192;
            const int i = rr >> 6, o = rr & 63;
            src = base + 8192 + o * 65 + 1 + i;
        } else if (r < 12352) {               // bc
            const int o = r - 12288;
            src = base + 8192 + o * 65;
        }
    } else {
        const int rr = d - 24832;
        const int base = RL * MID_DIM;        // 24704
        if (rr < 64)        { src = base + rr * 2;            scale = INV2PI; }
        else if (rr < 128)  { src = base + (rr - 64) * 2 + 1; scale = INV2PI; }
        else if (rr < 192)  { src = base + 128 + 1 + (rr - 128); }
        else if (rr == 192) { src = base + 128; }
    }
    float v = 0.f;
    if (src >= 0) {
        v = b3[src];
        #pragma unroll
        for (int j = 0; j < KSPLIT3; ++j)
            v += p3[(size_t)(j * 4 + b) * MLP_OUT + src];
        v *= scale;
    }
    mlpT[(size_t)b * MLPT_STRIDE + d] = v;
}

// ============================================================================
// k_ripple: fully fused ripple.  grid (SEQ/32, B), block 256.  [verified]
// ============================================================================
__global__ void __launch_bounds__(256, 2) k_ripple(
        const float* __restrict__ mlpT, const float* __restrict__ lcw,
        const float* __restrict__ lcb, const float* __restrict__ bypw,
        const float* __restrict__ bypb, float* __restrict__ out) {
    const int tid = threadIdx.x;
    const int b = blockIdx.y;
    const int t0 = blockIdx.x * 32;
    const int lane = tid & 63, wid = tid >> 6, tb = wid * 8;

    __shared__ __align__(16) float s_w[12416];
    __shared__ __align__(16) float s_x[64 * 36];
    __shared__ __align__(16) float s_wo[256];
    __shared__ float s_red[32];

    const float* mb = mlpT + (size_t)b * MLPT_STRIDE;

    {
        const float4* src = reinterpret_cast<const float4*>(mb);
        float4* dst = reinterpret_cast<float4*>(s_w);
        for (int e = tid; e < 3104; e += 256) dst[e] = src[e];
        if (tid < 64) {
            reinterpret_cast<float4*>(s_wo)[tid] =
                reinterpret_cast<const float4*>(mb + 24832)[tid];
        }
    }
    const float lw = lcw[lane], lb = lcb[lane];
    for (int e = tid; e < 2048; e += 256) {
        const int i = e >> 5, tt = e & 31;
        s_x[i * 36 + tt] = fmaf((float)(t0 + tt), lcw[i], lcb[i]);
    }
    __syncthreads();

    float acc[8];
    for (int layer = 0; layer < 2; ++layer) {
        const float bc = s_w[12288 + lane];
        #pragma unroll
        for (int j = 0; j < 8; ++j) acc[j] = bc;
        for (int i = 0; i < 64; ++i) {
            const float ws_ = s_w[i * 64 + lane];
            const float wo_ = s_w[4096 + i * 64 + lane];
            const float bs_ = s_w[8192 + i * 64 + lane];
            const float4 xa = *reinterpret_cast<const float4*>(&s_x[i * 36 + tb]);
            const float4 xb = *reinterpret_cast<const float4*>(&s_x[i * 36 + tb + 4]);
            const float xv[8] = {xa.x, xa.y, xa.z, xa.w, xb.x, xb.y, xb.z, xb.w};
            #pragma unroll
            for (int j = 0; j < 8; ++j) {
                const float r = fmaf(ws_, xv[j], wo_);
                acc[j] = fmaf(hw_sin_rev(r), bs_, acc[j]);
            }
        }
        __syncthreads();
        if (layer == 0) {
            #pragma unroll
            for (int j = 0; j < 8; ++j)
                s_x[lane * 36 + tb + j] = gelu_exact(acc[j]);
            const float4* src = reinterpret_cast<const float4*>(mb + 12416);
            float4* dst = reinterpret_cast<float4*>(s_w);
            for (int e = tid; e < 3104; e += 256) dst[e] = src[e];
            __syncthreads();
        }
    }

    {
        const float wsO = s_wo[lane], woO = s_wo[64 + lane], bsO = s_wo[128 + lane];
        const float bcO = s_wo[192];
        const float bw0 = bypw[0] * INV2PI, bw1 = bypw[1] * INV2PI;
        const float bb0 = bypb[0], bb1 = bypb[1];
        #pragma unroll
        for (int j = 0; j < 8; ++j) {
            const int t = t0 + tb + j;
            const float v = gelu_exact(acc[j]);
            float s = hw_sin_rev(fmaf(wsO, v, woO)) * bsO;
            const float xbv = fmaf((float)t, lw, lb);
            s = fmaf(hw_sin_rev(fmaf(bw0, xbv, bw1)), bb1, s);
            #pragma unroll
            for (int m = 1; m < 64; m <<= 1) s += __shfl_xor(s, m, 64);
            if (lane == 0) s_red[tb + j] = s + bcO + bb0;
        }
    }
    __syncthreads();
    if (tid < 32) out[(size_t)b * SEQ + t0 + tid] = s_red[tid];
}

extern "C" void kernel_launch(void* const* d_in, const int* in_sizes, int n_in,
                              void* d_out, int out_size, void* d_ws, size_t ws_size,
                              hipStream_t stream) {
    const float* x     = (const float*)d_in[0];
    const float* w0    = (const float*)d_in[1];
    const float* b0    = (const float*)d_in[2];
    const float* w1    = (const float*)d_in[3];
    const float* b1    = (const float*)d_in[4];
    const float* g1    = (const float*)d_in[5];
    const float* bln1  = (const float*)d_in[6];
    const float* w2    = (const float*)d_in[7];
    const float* b2    = (const float*)d_in[8];
    const float* g2    = (const float*)d_in[9];
    const float* bln2  = (const float*)d_in[10];
    const float* w3    = (const float*)d_in[11];
    const float* b3    = (const float*)d_in[12];
    const float* lcw   = (const float*)d_in[13];
    const float* lcb   = (const float*)d_in[14];
    const float* bypw  = (const float*)d_in[15];
    const float* bypb  = (const float*)d_in[16];
    float* out = (float*)d_out;
    float* ws  = (float*)d_ws;

    float* p0   = ws + OFF_P0;
    float* p1   = ws + OFF_P1;
    float* p2   = ws + OFF_P2;
    float* h2   = ws + OFF_H2;
    float* p3   = ws + OFF_P3;
    float* mlpT = ws + OFF_MLPT;

    k_gemm0  <<<dim3(16, 8),        256, 0, stream>>>(x, w0, p0);
    k_gemm1  <<<dim3(16, 16),       256, 0, stream>>>(p0, b0, w1, p1);
    k_B      <<<dim3(16, 16),       256, 0, stream>>>(p1, b1, g1, bln1, w2, p2);
    k_lng    <<<B_, 1024,           0, stream>>>(p2, b2, g2, bln2, h2);
    k_gemm3s <<<dim3(98, KSPLIT3),  256, 0, stream>>>(h2, w3, p3);
    k_comb3T <<<dim3(98, B_),       256, 0, stream>>>(p3, b3, mlpT);
    k_ripple <<<dim3(SEQ / 32, B_), 256, 0, stream>>>(mlpT, lcw, lcb, bypw, bypb, out);
}